// Round 4
// baseline (62.377 us; speedup 1.0000x reference)
//
#include <hip/hip_runtime.h>

// DistanceTransform closed form (verified absmax=0.0 in rounds 1-3):
//   d(p)  = Chebyshev (L_inf) distance to nearest seed (replicate-pad => clamp)
//   out(p)= 0 if d==0 else (d-1) - 0.35*log(a*w1 + c*w2)
// where a/c = # edge/corner 3x3 taps whose CLAMPED source pixel has d < d(p),
// w1 = exp(-1/0.35), w2 = exp(-sqrt(2)/0.35).
//
// Round-4: ONE dispatch. Each block re-derives the seed list from the image
// (register-only bitmask scan, no atomics in the load loop -- R2's mistake),
// then Chebyshev + epilogue for its own 16x32 output patch.

#define RG_H  18                 // 16 + 2 halo
#define RG_W  34                 // 32 + 2 halo
#define RGSZ  (RG_H * RG_W)      // 612
#define SEED_CAP 512

__global__ __launch_bounds__(256) void k_all(const float* __restrict__ img,
                                             float* __restrict__ out) {
    __shared__ unsigned short slist[SEED_CAP];
    __shared__ int scount;
    __shared__ unsigned char sd[RGSZ];

    const int t  = threadIdx.x;
    const int b  = blockIdx.x;        // 0..255
    const int n  = b >> 7;            // image 0/1
    const int p  = b & 127;           // patch: 16 rows x 8 cols of 16x32 patches
    const int y0 = (p >> 3) * 16;
    const int x0 = (p & 7) * 32;

    if (t == 0) scount = 0;           // visibility guaranteed by the sync below

    // ---- Phase 0: register-only scan of own image -> 64-bit group mask ----
    // thread t, iter it covers float4 #(it*256+t); bit it = any nonzero.
    const float4* im4 = reinterpret_cast<const float4*>(img + (n << 16));
    unsigned long long gm = 0ull;
    #pragma unroll 16
    for (int it = 0; it < 64; ++it) {
        const float4 v = im4[(it << 8) + t];
        const bool nz = (v.x != 0.0f) | (v.y != 0.0f) |
                        (v.z != 0.0f) | (v.w != 0.0f);
        gm |= (unsigned long long)nz << it;
    }
    __syncthreads();                  // scount=0 visible; scans complete

    // ---- Phase 1: extract seeds (rare; ~66 set bits across whole block) ----
    while (gm) {
        const int it = __ffsll(gm) - 1;
        gm &= gm - 1;
        const int f4 = (it << 8) + t;
        const float4 v = im4[f4];     // L1 hit (just read in phase 0)
        const int base = f4 << 2;     // flat pixel = y*256 + x
        if (v.x != 0.0f) { int i_ = atomicAdd(&scount, 1); if (i_ < SEED_CAP) slist[i_] = (unsigned short)(base    ); }
        if (v.y != 0.0f) { int i_ = atomicAdd(&scount, 1); if (i_ < SEED_CAP) slist[i_] = (unsigned short)(base + 1); }
        if (v.z != 0.0f) { int i_ = atomicAdd(&scount, 1); if (i_ < SEED_CAP) slist[i_] = (unsigned short)(base + 2); }
        if (v.w != 0.0f) { int i_ = atomicAdd(&scount, 1); if (i_ < SEED_CAP) slist[i_] = (unsigned short)(base + 3); }
    }
    __syncthreads();
    const int cnt = min(scount, SEED_CAP);

    // ---- Phase 2: Chebyshev DT over 18x34 halo'd region (clamped coords) ----
    // 612 cells, 3 accumulators/thread. Clamping reproduces replicate-pad.
    int gy[3], gx[3], best[3];
    #pragma unroll
    for (int k = 0; k < 3; ++k) {
        const int r  = t + (k << 8);
        const int rr = (r < RGSZ) ? r : 0;
        const int ry = rr / RG_W;
        const int rx = rr - ry * RG_W;
        gy[k] = min(max(y0 - 1 + ry, 0), 255);
        gx[k] = min(max(x0 - 1 + rx, 0), 255);
        best[k] = 1023;
    }
    for (int s = 0; s < cnt; ++s) {
        const int sp = slist[s];      // LDS broadcast (same address all lanes)
        const int sy = sp >> 8;
        const int sx = sp & 255;
        #pragma unroll
        for (int k = 0; k < 3; ++k) {
            int dy = gy[k] - sy; dy = (dy < 0) ? -dy : dy;
            int dx = gx[k] - sx; dx = (dx < 0) ? -dx : dx;
            best[k] = min(best[k], max(dy, dx));
        }
    }
    #pragma unroll
    for (int k = 0; k < 3; ++k) {
        const int r = t + (k << 8);
        if (r < RGSZ) sd[r] = (unsigned char)best[k];   // d <= 255 (seed @ (0,0))
    }
    __syncthreads();

    // ---- Phase 3: epilogue, 2 output pixels per thread (identical math) ----
    const float W1 = expf(-(1.0f / 0.35f));            // edge tap weight
    const float W2 = expf(-(1.41421356f / 0.35f));     // corner tap weight
    #pragma unroll
    for (int j = 0; j < 2; ++j) {
        const int pi = t + (j << 8);                   // 0..511 in 16x32 patch
        const int ly = pi >> 5;
        const int lx = pi & 31;
        const int rc = (ly + 1) * RG_W + (lx + 1);
        const int dp = sd[rc];
        const int a =
            (sd[rc - RG_W] < dp) + (sd[rc + RG_W] < dp) +
            (sd[rc - 1   ] < dp) + (sd[rc + 1   ] < dp);
        const int c =
            (sd[rc - RG_W - 1] < dp) + (sd[rc - RG_W + 1] < dp) +
            (sd[rc + RG_W - 1] < dp) + (sd[rc + RG_W + 1] < dp);
        const float S = (float)a * W1 + (float)c * W2;  // > 0 whenever dp > 0
        const float v = (float)(dp - 1) - 0.35f * logf(S);
        out[(n << 16) + ((y0 + ly) << 8) + (x0 + lx)] = (dp > 0) ? v : 0.0f;
    }
}

extern "C" void kernel_launch(void* const* d_in, const int* in_sizes, int n_in,
                              void* d_out, int out_size, void* d_ws, size_t ws_size,
                              hipStream_t stream) {
    const float* img = (const float*)d_in[0];
    float* out = (float*)d_out;
    k_all<<<256, 256, 0, stream>>>(img, out);
}